// Round 3
// baseline (894.474 us; speedup 1.0000x reference)
//
#include <hip/hip_runtime.h>
#include <hip/hip_bf16.h>

// Qwen2 decoder-layer fragment (Q path only — K/V are dead downstream):
//   h = rmsnorm(x, ln_w); q = h@Wq^T + bq; q = rope(q, pos); out = q@Wo^T + x
// out fp32 [8192, 3584].

#define HIDDEN   3584
#define NQ       3584
#define NTOK     8192
#define NPAIR    64
#define EPSV     1e-6f

typedef __hip_bfloat16 bf16;
typedef __bf16 bf16x8 __attribute__((ext_vector_type(8)));
typedef float  f32x4  __attribute__((ext_vector_type(4)));

static __device__ __forceinline__ unsigned short f2bu(float f) {
  bf16 h = __float2bfloat16(f);
  return __builtin_bit_cast(unsigned short, h);
}
static __device__ __forceinline__ void stv(float* p, float v) { *p = v; }
static __device__ __forceinline__ void stv(bf16* p, float v) { *p = __float2bfloat16(v); }

// ---------------- fp32 -> bf16 weight conversion ----------------
__global__ __launch_bounds__(256)
void cvt_f32_bf16(const float* __restrict__ s, bf16* __restrict__ d, int n4) {
  int i = blockIdx.x * 256 + threadIdx.x;
  if (i >= n4) return;
  float4 f = ((const float4*)s)[i];
  ushort4 o;
  o.x = f2bu(f.x); o.y = f2bu(f.y); o.z = f2bu(f.z); o.w = f2bu(f.w);
  ((ushort4*)d)[i] = o;
}

// ---------------- RMSNorm: x fp32 [row, 3584] -> h bf16 ----------------
__global__ __launch_bounds__(256)
void rmsnorm_k(const float* __restrict__ x, const float* __restrict__ w,
               bf16* __restrict__ h) {
  const int row = blockIdx.x;
  const int t = threadIdx.x;
  const float4* xr = (const float4*)(x + (size_t)row * HIDDEN);
  const float4* wr = (const float4*)w;

  float4 v0 = xr[t], v1 = xr[t + 256], v2 = xr[t + 512];
  float4 v3 = make_float4(0.f, 0.f, 0.f, 0.f);
  if (t < 128) v3 = xr[t + 768];

  float ss = v0.x*v0.x + v0.y*v0.y + v0.z*v0.z + v0.w*v0.w
           + v1.x*v1.x + v1.y*v1.y + v1.z*v1.z + v1.w*v1.w
           + v2.x*v2.x + v2.y*v2.y + v2.z*v2.z + v2.w*v2.w
           + v3.x*v3.x + v3.y*v3.y + v3.z*v3.z + v3.w*v3.w;

#pragma unroll
  for (int off = 32; off > 0; off >>= 1) ss += __shfl_down(ss, off);
  __shared__ float red[4];
  if ((t & 63) == 0) red[t >> 6] = ss;
  __syncthreads();
  float tot = red[0] + red[1] + red[2] + red[3];
  float scale = rsqrtf(tot * (1.0f / HIDDEN) + EPSV);

  ushort4* hr = (ushort4*)(h + (size_t)row * HIDDEN);
  float4 w0 = wr[t], w1 = wr[t + 256], w2 = wr[t + 512];
  ushort4 o;
  o.x = f2bu(v0.x*scale*w0.x); o.y = f2bu(v0.y*scale*w0.y);
  o.z = f2bu(v0.z*scale*w0.z); o.w = f2bu(v0.w*scale*w0.w);
  hr[t] = o;
  o.x = f2bu(v1.x*scale*w1.x); o.y = f2bu(v1.y*scale*w1.y);
  o.z = f2bu(v1.z*scale*w1.z); o.w = f2bu(v1.w*scale*w1.w);
  hr[t + 256] = o;
  o.x = f2bu(v2.x*scale*w2.x); o.y = f2bu(v2.y*scale*w2.y);
  o.z = f2bu(v2.z*scale*w2.z); o.w = f2bu(v2.w*scale*w2.w);
  hr[t + 512] = o;
  if (t < 128) {
    float4 w3 = wr[t + 768];
    o.x = f2bu(v3.x*scale*w3.x); o.y = f2bu(v3.y*scale*w3.y);
    o.z = f2bu(v3.z*scale*w3.z); o.w = f2bu(v3.w*scale*w3.w);
    hr[t + 768] = o;
  }
}

// ---------------- per-token rope table ----------------
__global__ __launch_bounds__(256)
void rope_tab_k(const int* __restrict__ pos, float2* __restrict__ tab) {
  int idx = blockIdx.x * 256 + threadIdx.x;   // NTOK*64
  int t = idx >> 6;
  int i = idx & 63;
  float inv = exp2f(-(float)i * (19.931568569324174f / 64.0f));
  float ang = (float)pos[t] * inv;
  float s, c;
  sincosf(ang, &s, &c);
  tab[idx] = make_float2(c, s);
}

// ---------------- in-place neox rope on q bf16 [NTOK, 28, 128] ----------------
__global__ __launch_bounds__(256)
void rope_apply_k(bf16* __restrict__ q, const float2* __restrict__ tab) {
  const int t = blockIdx.x;
  bf16* qt = q + (size_t)t * NQ;
  const float2* tb = tab + (size_t)t * NPAIR;
  for (int j = threadIdx.x; j < 28 * NPAIR; j += 256) {
    int head = j >> 6;
    int i = j & 63;
    float2 cs = tb[i];
    int base = head * 128 + i;
    float x1 = __bfloat162float(qt[base]);
    float x2 = __bfloat162float(qt[base + 64]);
    qt[base]      = __float2bfloat16(x1 * cs.x - x2 * cs.y);
    qt[base + 64] = __float2bfloat16(x2 * cs.x + x1 * cs.y);
  }
}

// ================= deep-pipelined 256x256 bf16 GEMM (C = A * B^T) ===========
// 8 waves (2M x 4N), BK=32 K-tiles, 4-deep circular LDS buffer (128 KiB),
// stage 2 tiles ahead, counted s_waitcnt vmcnt(4) (never 0 in main loop),
// raw s_barrier (no compiler vmcnt(0) drain), setprio around MFMA clusters,
// k-slot XOR swizzle (pre-swizzled global source + swizzled ds_read; LDS dest
// linear per gload_lds rules), bijective XCD blockIdx swizzle.
// Pipeline safety: per-wave in-order load completion => vmcnt(4) at end of
// tile t (4 newest = tile t+2's loads) guarantees tile t+1 landed. Buffer
// (t+2)&3 was last read by tile t-2, which finished >=2 barriers before the
// tile-t stage issue => no WAR race.
#define BMT 256
#define BNT 256
#define BKT 32
#define NBUF 4

#define FENCE() asm volatile("" ::: "memory")
#define BAR() do { FENCE(); __builtin_amdgcn_s_barrier(); FENCE(); } while (0)

template <int MODE, typename OutT>   // MODE 0: +bias[col] -> OutT; MODE 1: +resid[row,col]
__global__ __launch_bounds__(512, 2)
void gemm256(const bf16* __restrict__ A, const bf16* __restrict__ B,
             const float* __restrict__ aux, OutT* __restrict__ C,
             int M, int N, int K) {
  __shared__ bf16 sA[NBUF][BMT][BKT];   // 64 KiB
  __shared__ bf16 sB[NBUF][BNT][BKT];   // 64 KiB

  const int tid  = threadIdx.x;
  const int wave = tid >> 6;     // 0..7
  const int lane = tid & 63;
  const int wm   = wave >> 2;    // 0..1  (M half)
  const int wn   = wave & 3;     // 0..3  (N quarter)

  // bijective XCD swizzle (gridDim.x % 8 == 0 for our shapes)
  const int nwg = gridDim.x;
  const int cpx = nwg >> 3;
  const int swz = (blockIdx.x & 7) * cpx + (blockIdx.x >> 3);
  const int gm  = M / BMT;
  const int bm  = (swz % gm) * BMT;    // m-fast: XCD neighbors share B panels
  const int bn  = (swz / gm) * BNT;

  const bf16* Ab = A + (size_t)bm * K;
  const bf16* Bb = B + (size_t)bn * K;

  // staging geometry: per wave-instr, lane l writes LDS bytes base + l*16
  // (row = l/4, k-slot = l%4 of a 16-row stripe). Global source pre-swizzled:
  // k-chunk = (l%4) ^ (row&3)  (involution, matches read-side swizzle).
  const int srow = lane >> 2;                       // 0..15 within stripe
  const int sk   = ((lane & 3) ^ (srow & 3)) * 8;   // swizzled k offset (elems)
  const int NTt  = K / BKT;

  auto stageA = [&](int kt) {
    if (kt >= NTt) return;
    const int b = kt & (NBUF - 1);
    const size_t gk = (size_t)kt * BKT + sk;
#pragma unroll
    for (int j = 0; j < 2; ++j) {
      const int r0 = wave * 32 + j * 16;
      const bf16* src = Ab + (size_t)(r0 + srow) * K + gk;
      __builtin_amdgcn_global_load_lds(
          (const __attribute__((address_space(1))) void*)src,
          (__attribute__((address_space(3))) void*)&sA[b][r0][0], 16, 0, 0);
    }
  };
  auto stageB = [&](int kt) {
    if (kt >= NTt) return;
    const int b = kt & (NBUF - 1);
    const size_t gk = (size_t)kt * BKT + sk;
#pragma unroll
    for (int j = 0; j < 2; ++j) {
      const int r0 = wave * 32 + j * 16;
      const bf16* src = Bb + (size_t)(r0 + srow) * K + gk;
      __builtin_amdgcn_global_load_lds(
          (const __attribute__((address_space(1))) void*)src,
          (__attribute__((address_space(3))) void*)&sB[b][r0][0], 16, 0, 0);
    }
  };

  f32x4 acc[8][4];
#pragma unroll
  for (int i = 0; i < 8; ++i)
#pragma unroll
    for (int j = 0; j < 4; ++j)
      acc[i][j] = (f32x4){0.f, 0.f, 0.f, 0.f};

  // fragment read: row = <frag base> + (lane&15); k-slot = (lane>>4) ^ (row&3)
  const int fr    = lane & 15;
  const int ks    = lane >> 4;
  const int rslot = (ks ^ (fr & 3)) * 8;   // element offset within LDS row

  // prologue: tiles 0,1 staged; vmcnt(4) => tile 0 fully landed
  stageA(0); stageB(0); stageA(1); stageB(1);
  asm volatile("s_waitcnt vmcnt(4)" ::: "memory");
  BAR();

  for (int t = 0; t < NTt; ++t) {
    const int b = t & (NBUF - 1);
    bf16x8 bfr[4], afr[4];

    // ---- phase 1: B frags + A(qm=0), MFMA upper half ----
    stageA(t + 2);
#pragma unroll
    for (int j = 0; j < 4; ++j)
      bfr[j] = *(const bf16x8*)&sB[b][wn * 64 + j * 16 + fr][rslot];
#pragma unroll
    for (int i = 0; i < 4; ++i)
      afr[i] = *(const bf16x8*)&sA[b][wm * 128 + i * 16 + fr][rslot];
    BAR();
    asm volatile("s_waitcnt lgkmcnt(0)" ::: "memory");
    __builtin_amdgcn_sched_barrier(0);
    __builtin_amdgcn_s_setprio(1);
#pragma unroll
    for (int i = 0; i < 4; ++i)
#pragma unroll
      for (int j = 0; j < 4; ++j)
        acc[i][j] = __builtin_amdgcn_mfma_f32_16x16x32_bf16(
            afr[i], bfr[j], acc[i][j], 0, 0, 0);
    __builtin_amdgcn_s_setprio(0);
    BAR();

    // ---- phase 2: A(qm=1), MFMA lower half ----
    stageB(t + 2);
#pragma unroll
    for (int i = 0; i < 4; ++i)
      afr[i] = *(const bf16x8*)&sA[b][wm * 128 + 64 + i * 16 + fr][rslot];
    BAR();
    asm volatile("s_waitcnt lgkmcnt(0)" ::: "memory");
    __builtin_amdgcn_sched_barrier(0);
    __builtin_amdgcn_s_setprio(1);
#pragma unroll
    for (int i = 0; i < 4; ++i)
#pragma unroll
      for (int j = 0; j < 4; ++j)
        acc[4 + i][j] = __builtin_amdgcn_mfma_f32_16x16x32_bf16(
            afr[i], bfr[j], acc[4 + i][j], 0, 0, 0);
    __builtin_amdgcn_s_setprio(0);
    if (t < NTt - 2) asm volatile("s_waitcnt vmcnt(4)" ::: "memory");
    else             asm volatile("s_waitcnt vmcnt(0)" ::: "memory");
    BAR();
  }

  // epilogue: C/D layout col = lane&15, row = 4*(lane>>4) + reg
  const int cb = bn + wn * 64 + fr;
#pragma unroll
  for (int qm = 0; qm < 2; ++qm)
#pragma unroll
    for (int i = 0; i < 4; ++i) {
      const int rb = bm + wm * 128 + qm * 64 + i * 16 + ks * 4;
#pragma unroll
      for (int j = 0; j < 4; ++j) {
        const int col = cb + j * 16;
#pragma unroll
        for (int r = 0; r < 4; ++r) {
          const int row = rb + r;
          float v = acc[qm * 4 + i][j][r];
          if (MODE == 0) v += aux[col];
          else           v += aux[(size_t)row * N + col];
          stv(&C[(size_t)row * N + col], v);
        }
      }
    }
}

// ---------------- launch ----------------
extern "C" void kernel_launch(void* const* d_in, const int* in_sizes, int n_in,
                              void* d_out, int out_size, void* d_ws, size_t ws_size,
                              hipStream_t stream) {
  (void)in_sizes; (void)n_in; (void)out_size; (void)ws_size;
  const float* x    = (const float*)d_in[0];
  const int*   pos  = (const int*)d_in[1];
  const float* ln_w = (const float*)d_in[2];
  const float* Wq   = (const float*)d_in[3];
  const float* bq   = (const float*)d_in[4];
  const float* Wo   = (const float*)d_in[9];
  float* out = (float*)d_out;

  char* ws = (char*)d_ws;
  size_t off = 0;
  bf16* h    = (bf16*)(ws + off); off += (size_t)NTOK * HIDDEN * sizeof(bf16);
  bf16* q    = (bf16*)(ws + off); off += (size_t)NTOK * NQ * sizeof(bf16);
  bf16* Wqb  = (bf16*)(ws + off); off += (size_t)NQ * HIDDEN * sizeof(bf16);
  bf16* Wob  = (bf16*)(ws + off); off += (size_t)HIDDEN * NQ * sizeof(bf16);
  float2* tab = (float2*)(ws + off); off += (size_t)NTOK * NPAIR * sizeof(float2);

  const int n4 = NQ * HIDDEN / 4;
  cvt_f32_bf16<<<(n4 + 255) / 256, 256, 0, stream>>>(Wq, Wqb, n4);
  cvt_f32_bf16<<<(n4 + 255) / 256, 256, 0, stream>>>(Wo, Wob, n4);
  rmsnorm_k<<<NTOK, 256, 0, stream>>>(x, ln_w, h);
  rope_tab_k<<<(NTOK * NPAIR) / 256, 256, 0, stream>>>(pos, tab);

  const int nblk = (NTOK / BMT) * (NQ / BNT);   // 32 * 14 = 448 (%8 == 0)
  gemm256<0, bf16><<<nblk, 512, 0, stream>>>(h, Wqb, bq, q, NTOK, NQ, HIDDEN);
  rope_apply_k<<<NTOK, 256, 0, stream>>>(q, tab);
  gemm256<1, float><<<nblk, 512, 0, stream>>>(q, Wob, x, out, NTOK, HIDDEN, NQ);
}

// Round 4
// 529.325 us; speedup vs baseline: 1.6898x; 1.6898x over previous
//
#include <hip/hip_runtime.h>
#include <hip/hip_bf16.h>

// Qwen2 decoder-layer fragment (Q path only — K/V are dead downstream):
//   h = rmsnorm(x, ln_w); q = h@Wq^T + bq; q = rope(q, pos); out = q@Wo^T + x
// out fp32 [8192, 3584].

#define HIDDEN   3584
#define NQ       3584
#define NTOK     8192
#define NPAIR    64
#define EPSV     1e-6f

typedef __hip_bfloat16 bf16;
typedef __bf16 bf16x8 __attribute__((ext_vector_type(8)));
typedef float  f32x4  __attribute__((ext_vector_type(4)));

static __device__ __forceinline__ unsigned short f2bu(float f) {
  bf16 h = __float2bfloat16(f);
  return __builtin_bit_cast(unsigned short, h);
}
static __device__ __forceinline__ void stv(float* p, float v) { *p = v; }
static __device__ __forceinline__ void stv(bf16* p, float v) { *p = __float2bfloat16(v); }

// ---------------- fp32 -> bf16 weight conversion ----------------
__global__ __launch_bounds__(256)
void cvt_f32_bf16(const float* __restrict__ s, bf16* __restrict__ d, int n4) {
  int i = blockIdx.x * 256 + threadIdx.x;
  if (i >= n4) return;
  float4 f = ((const float4*)s)[i];
  ushort4 o;
  o.x = f2bu(f.x); o.y = f2bu(f.y); o.z = f2bu(f.z); o.w = f2bu(f.w);
  ((ushort4*)d)[i] = o;
}

// ---------------- RMSNorm: x fp32 [row, 3584] -> h bf16 ----------------
__global__ __launch_bounds__(256)
void rmsnorm_k(const float* __restrict__ x, const float* __restrict__ w,
               bf16* __restrict__ h) {
  const int row = blockIdx.x;
  const int t = threadIdx.x;
  const float4* xr = (const float4*)(x + (size_t)row * HIDDEN);
  const float4* wr = (const float4*)w;

  float4 v0 = xr[t], v1 = xr[t + 256], v2 = xr[t + 512];
  float4 v3 = make_float4(0.f, 0.f, 0.f, 0.f);
  if (t < 128) v3 = xr[t + 768];

  float ss = v0.x*v0.x + v0.y*v0.y + v0.z*v0.z + v0.w*v0.w
           + v1.x*v1.x + v1.y*v1.y + v1.z*v1.z + v1.w*v1.w
           + v2.x*v2.x + v2.y*v2.y + v2.z*v2.z + v2.w*v2.w
           + v3.x*v3.x + v3.y*v3.y + v3.z*v3.z + v3.w*v3.w;

#pragma unroll
  for (int off = 32; off > 0; off >>= 1) ss += __shfl_down(ss, off);
  __shared__ float red[4];
  if ((t & 63) == 0) red[t >> 6] = ss;
  __syncthreads();
  float tot = red[0] + red[1] + red[2] + red[3];
  float scale = rsqrtf(tot * (1.0f / HIDDEN) + EPSV);

  ushort4* hr = (ushort4*)(h + (size_t)row * HIDDEN);
  float4 w0 = wr[t], w1 = wr[t + 256], w2 = wr[t + 512];
  ushort4 o;
  o.x = f2bu(v0.x*scale*w0.x); o.y = f2bu(v0.y*scale*w0.y);
  o.z = f2bu(v0.z*scale*w0.z); o.w = f2bu(v0.w*scale*w0.w);
  hr[t] = o;
  o.x = f2bu(v1.x*scale*w1.x); o.y = f2bu(v1.y*scale*w1.y);
  o.z = f2bu(v1.z*scale*w1.z); o.w = f2bu(v1.w*scale*w1.w);
  hr[t + 256] = o;
  o.x = f2bu(v2.x*scale*w2.x); o.y = f2bu(v2.y*scale*w2.y);
  o.z = f2bu(v2.z*scale*w2.z); o.w = f2bu(v2.w*scale*w2.w);
  hr[t + 512] = o;
  if (t < 128) {
    float4 w3 = wr[t + 768];
    o.x = f2bu(v3.x*scale*w3.x); o.y = f2bu(v3.y*scale*w3.y);
    o.z = f2bu(v3.z*scale*w3.z); o.w = f2bu(v3.w*scale*w3.w);
    hr[t + 768] = o;
  }
}

// ---------------- per-token rope table ----------------
__global__ __launch_bounds__(256)
void rope_tab_k(const int* __restrict__ pos, float2* __restrict__ tab) {
  int idx = blockIdx.x * 256 + threadIdx.x;   // NTOK*64
  int t = idx >> 6;
  int i = idx & 63;
  float inv = exp2f(-(float)i * (19.931568569324174f / 64.0f));
  float ang = (float)pos[t] * inv;
  float s, c;
  sincosf(ang, &s, &c);
  tab[idx] = make_float2(c, s);
}

// ---------------- in-place neox rope on q bf16 [NTOK, 28, 128] ----------------
__global__ __launch_bounds__(256)
void rope_apply_k(bf16* __restrict__ q, const float2* __restrict__ tab) {
  const int t = blockIdx.x;
  bf16* qt = q + (size_t)t * NQ;
  const float2* tb = tab + (size_t)t * NPAIR;
  for (int j = threadIdx.x; j < 28 * NPAIR; j += 256) {
    int head = j >> 6;
    int i = j & 63;
    float2 cs = tb[i];
    int base = head * 128 + i;
    float x1 = __bfloat162float(qt[base]);
    float x2 = __bfloat162float(qt[base + 64]);
    qt[base]      = __float2bfloat16(x1 * cs.x - x2 * cs.y);
    qt[base + 64] = __float2bfloat16(x2 * cs.x + x1 * cs.y);
  }
}

// ================= 256x256 8-phase bf16 GEMM (C = A * B^T), m201 port =======
// 8 waves (2M x 4N), BK=64 K-tiles, double-buffered LDS (128 KiB).
// Per iter (2 K-tiles, 8 phases): each phase = {ds_read frags | stage 16KB
// (2 gload_lds/wave) | barrier | lgkmcnt(0) | setprio+16 MFMA | barrier}.
// Staging staggered into dead regions: B of a tile dead after its phase 1;
// A half H0{rows 0-63,128-191} dead after phase 2, H1{64-127,192-255} after
// phase 4. Counted vmcnt(6) only at phases 4/8 (3 x 16KB half-tiles in
// flight, 2 loads each); vmcnt(0) only in the endgame.
// Swizzle: slot' = slot ^ ((row&12)>>1) (involution). gload_lds dest linear,
// global source pre-swizzled, ds_read swizzled -> uniform 8 lanes per 4-bank
// group = 2-way = free.
#define BMT 256
#define BNT 256
#define BKT 64

#define FENCE() asm volatile("" ::: "memory")
#define BAR() do { FENCE(); __builtin_amdgcn_s_barrier(); FENCE(); } while (0)

template <int MODE, typename OutT>   // MODE 0: +bias[col] -> OutT; MODE 1: +resid[row,col]
__global__ __launch_bounds__(512, 2)
void gemm256(const bf16* __restrict__ A, const bf16* __restrict__ B,
             const float* __restrict__ aux, OutT* __restrict__ C,
             int M, int N, int K) {
  __shared__ __align__(16) bf16 sA[2][BMT][BKT];   // 64 KiB
  __shared__ __align__(16) bf16 sB[2][BNT][BKT];   // 64 KiB

  const int tid  = threadIdx.x;
  const int wave = tid >> 6;     // 0..7
  const int lane = tid & 63;
  const int wm   = wave >> 2;    // 0..1
  const int wn   = wave & 3;     // 0..3
  const int fr   = lane & 15;
  const int ks   = lane >> 4;
  const int sx   = (fr & 12) >> 1;   // read-side slot XOR (row&12)>>1

  // bijective XCD swizzle, bn-fast within an XCD (A panel hot in XCD L2)
  const int nwg = gridDim.x;           // 448, % 8 == 0
  const int cpx = nwg >> 3;
  const int swz = (blockIdx.x & 7) * cpx + (blockIdx.x >> 3);
  const int gn  = N / BNT;
  const int bm  = (swz / gn) * BMT;
  const int bn  = (swz % gn) * BNT;

  const bf16* Ab = A + (size_t)bm * K;
  const bf16* Bb = B + (size_t)bn * K;

  const int NT = K / BKT;   // 56 (even)

  // one 64-row chunk (8KB): wave w rows [rbase+w*8,+8); lane: row=l>>3, slot=l&7
  const int srw = lane >> 3;    // 0..7
  const int ssl = lane & 7;

  auto stage64 = [&](const bf16* gpanel, int kt, bf16* ldst, int rbase) {
    const int r  = rbase + wave * 8 + srw;            // tile-local row
    const int sg = ssl ^ ((r & 12) >> 1);             // pre-swizzled source slot
    const bf16* src = gpanel + (size_t)r * K + (size_t)kt * BKT + sg * 8;
    __builtin_amdgcn_global_load_lds(
        (const __attribute__((address_space(1))) void*)src,
        (__attribute__((address_space(3))) void*)(ldst + (size_t)(wave * 8) * BKT),
        16, 0, 0);
  };
  // kinds: 0=A_H0{0,128}, 1=A_H1{64,192}, 2=B_lo{0,64}, 3=B_hi{128,192}
  auto stage16k = [&](int kind, int buf, int kt) {
    if (kt >= NT) return;
    if (kind == 0)      { stage64(Ab, kt, &sA[buf][0][0],   0);   stage64(Ab, kt, &sA[buf][128][0], 128); }
    else if (kind == 1) { stage64(Ab, kt, &sA[buf][64][0],  64);  stage64(Ab, kt, &sA[buf][192][0], 192); }
    else if (kind == 2) { stage64(Bb, kt, &sB[buf][0][0],   0);   stage64(Bb, kt, &sB[buf][64][0],  64); }
    else                { stage64(Bb, kt, &sB[buf][128][0], 128); stage64(Bb, kt, &sB[buf][192][0], 192); }
  };

  f32x4 acc[8][4];
#pragma unroll
  for (int i = 0; i < 8; ++i)
#pragma unroll
    for (int j = 0; j < 4; ++j)
      acc[i][j] = (f32x4){0.f, 0.f, 0.f, 0.f};

  // prologue: tile0 complete (8 loads/wave), tile1 B + A_H0 (6 loads/wave)
  stage16k(2, 0, 0); stage16k(3, 0, 0); stage16k(0, 0, 0); stage16k(1, 0, 0);
  stage16k(2, 1, 1); stage16k(3, 1, 1); stage16k(0, 1, 1);
  asm volatile("s_waitcnt vmcnt(6)" ::: "memory");   // tile0 landed
  BAR();

  bf16x8 bfr[4][2];

  for (int it = 0; it < NT / 2; ++it) {
#pragma unroll
    for (int u = 0; u < 2; ++u) {          // buf/tile half: tile kt = 2*it+u
#pragma unroll
      for (int q = 0; q < 4; ++q) {        // phase within tile
        // ---- ds_read fragments for this phase ----
        bf16x8 afr[2][2];
#pragma unroll
        for (int i = 0; i < 2; ++i)
#pragma unroll
          for (int kk = 0; kk < 2; ++kk) {
            const int R  = wm * 128 + q * 32 + i * 16 + fr;
            const int sp = (kk * 4 + ks) ^ sx;
            afr[i][kk] = *(const bf16x8*)&sA[u][R][sp * 8];
          }
        if (q == 0) {
#pragma unroll
          for (int j = 0; j < 4; ++j)
#pragma unroll
            for (int kk = 0; kk < 2; ++kk) {
              const int R  = wn * 64 + j * 16 + fr;
              const int sp = (kk * 4 + ks) ^ sx;
              bfr[j][kk] = *(const bf16x8*)&sB[u][R][sp * 8];
            }
        }
        // ---- staggered 16KB stage (targets proven-dead regions) ----
        const int ph = u * 4 + q;
        if (ph == 0)      stage16k(1, 1, 2 * it + 1);   // A_H1 of tile 2it+1
        else if (ph == 1) stage16k(2, 0, 2 * it + 2);   // B_lo  tile 2it+2
        else if (ph == 2) stage16k(3, 0, 2 * it + 2);   // B_hi
        else if (ph == 3) stage16k(0, 0, 2 * it + 2);   // A_H0
        else if (ph == 4) stage16k(1, 0, 2 * it + 2);   // A_H1
        else if (ph == 5) stage16k(2, 1, 2 * it + 3);   // B_lo  tile 2it+3
        else if (ph == 6) stage16k(3, 1, 2 * it + 3);   // B_hi
        else              stage16k(0, 1, 2 * it + 3);   // A_H0
        if (q == 0) asm volatile("s_waitcnt lgkmcnt(8)" ::: "memory");  // 12 reads issued
        BAR();
        asm volatile("s_waitcnt lgkmcnt(0)" ::: "memory");
        __builtin_amdgcn_sched_barrier(0);
        __builtin_amdgcn_s_setprio(1);
#pragma unroll
        for (int i = 0; i < 2; ++i)
#pragma unroll
          for (int j = 0; j < 4; ++j)
#pragma unroll
            for (int kk = 0; kk < 2; ++kk)
              acc[q * 2 + i][j] = __builtin_amdgcn_mfma_f32_16x16x32_bf16(
                  afr[i][kk], bfr[j][kk], acc[q * 2 + i][j], 0, 0, 0);
        __builtin_amdgcn_s_setprio(0);
        if (q == 3) {
          const int ktn = 2 * it + 2 + u;  // tile whose stages were just issued
          if (ktn < NT) asm volatile("s_waitcnt vmcnt(6)" ::: "memory");
          else          asm volatile("s_waitcnt vmcnt(0)" ::: "memory");
        }
        BAR();
      }
    }
  }

  // epilogue: C/D layout col = lane&15, row = 4*(lane>>4) + reg
#pragma unroll
  for (int f = 0; f < 8; ++f) {
    const int rb = bm + wm * 128 + f * 16 + ks * 4;
#pragma unroll
    for (int j = 0; j < 4; ++j) {
      const int col = bn + wn * 64 + j * 16 + fr;
#pragma unroll
      for (int r = 0; r < 4; ++r) {
        const int row = rb + r;
        float v = acc[f][j][r];
        if (MODE == 0) v += aux[col];
        else           v += aux[(size_t)row * N + col];
        stv(&C[(size_t)row * N + col], v);
      }
    }
  }
}

// ---------------- launch ----------------
extern "C" void kernel_launch(void* const* d_in, const int* in_sizes, int n_in,
                              void* d_out, int out_size, void* d_ws, size_t ws_size,
                              hipStream_t stream) {
  (void)in_sizes; (void)n_in; (void)out_size; (void)ws_size;
  const float* x    = (const float*)d_in[0];
  const int*   pos  = (const int*)d_in[1];
  const float* ln_w = (const float*)d_in[2];
  const float* Wq   = (const float*)d_in[3];
  const float* bq   = (const float*)d_in[4];
  const float* Wo   = (const float*)d_in[9];
  float* out = (float*)d_out;

  char* ws = (char*)d_ws;
  size_t off = 0;
  bf16* h    = (bf16*)(ws + off); off += (size_t)NTOK * HIDDEN * sizeof(bf16);
  bf16* q    = (bf16*)(ws + off); off += (size_t)NTOK * NQ * sizeof(bf16);
  bf16* Wqb  = (bf16*)(ws + off); off += (size_t)NQ * HIDDEN * sizeof(bf16);
  bf16* Wob  = (bf16*)(ws + off); off += (size_t)HIDDEN * NQ * sizeof(bf16);
  float2* tab = (float2*)(ws + off); off += (size_t)NTOK * NPAIR * sizeof(float2);

  const int n4 = NQ * HIDDEN / 4;
  cvt_f32_bf16<<<(n4 + 255) / 256, 256, 0, stream>>>(Wq, Wqb, n4);
  cvt_f32_bf16<<<(n4 + 255) / 256, 256, 0, stream>>>(Wo, Wob, n4);
  rmsnorm_k<<<NTOK, 256, 0, stream>>>(x, ln_w, h);
  rope_tab_k<<<(NTOK * NPAIR) / 256, 256, 0, stream>>>(pos, tab);

  const int nblk = (NTOK / BMT) * (NQ / BNT);   // 32 * 14 = 448 (%8 == 0)
  gemm256<0, bf16><<<nblk, 512, 0, stream>>>(h, Wqb, bq, q, NTOK, NQ, HIDDEN);
  rope_apply_k<<<NTOK, 256, 0, stream>>>(q, tab);
  gemm256<1, float><<<nblk, 512, 0, stream>>>(q, Wob, x, out, NTOK, HIDDEN, NQ);
}

// Round 5
// 501.076 us; speedup vs baseline: 1.7851x; 1.0564x over previous
//
#include <hip/hip_runtime.h>
#include <hip/hip_bf16.h>

// Qwen2 decoder-layer fragment (Q path only — K/V are dead downstream):
//   h = rmsnorm(x, ln_w); q = h@Wq^T + bq; q = rope(q, pos); out = q@Wo^T + x
// out fp32 [8192, 3584].

#define HIDDEN   3584
#define NQ       3584
#define NTOK     8192
#define NPAIR    64
#define EPSV     1e-6f

typedef __hip_bfloat16 bf16;
typedef __bf16 bf16x8 __attribute__((ext_vector_type(8)));
typedef float  f32x4  __attribute__((ext_vector_type(4)));

static __device__ __forceinline__ unsigned short f2bu(float f) {
  bf16 h = __float2bfloat16(f);
  return __builtin_bit_cast(unsigned short, h);
}
static __device__ __forceinline__ void stv(float* p, float v) { *p = v; }
static __device__ __forceinline__ void stv(bf16* p, float v) { *p = __float2bfloat16(v); }

// ---------------- fp32 -> bf16 weight conversion ----------------
__global__ __launch_bounds__(256)
void cvt_f32_bf16(const float* __restrict__ s, bf16* __restrict__ d, int n4) {
  int i = blockIdx.x * 256 + threadIdx.x;
  if (i >= n4) return;
  float4 f = ((const float4*)s)[i];
  ushort4 o;
  o.x = f2bu(f.x); o.y = f2bu(f.y); o.z = f2bu(f.z); o.w = f2bu(f.w);
  ((ushort4*)d)[i] = o;
}

// ---------------- RMSNorm: x fp32 [row, 3584] -> h bf16 ----------------
__global__ __launch_bounds__(256)
void rmsnorm_k(const float* __restrict__ x, const float* __restrict__ w,
               bf16* __restrict__ h) {
  const int row = blockIdx.x;
  const int t = threadIdx.x;
  const float4* xr = (const float4*)(x + (size_t)row * HIDDEN);
  const float4* wr = (const float4*)w;

  float4 v0 = xr[t], v1 = xr[t + 256], v2 = xr[t + 512];
  float4 v3 = make_float4(0.f, 0.f, 0.f, 0.f);
  if (t < 128) v3 = xr[t + 768];

  float ss = v0.x*v0.x + v0.y*v0.y + v0.z*v0.z + v0.w*v0.w
           + v1.x*v1.x + v1.y*v1.y + v1.z*v1.z + v1.w*v1.w
           + v2.x*v2.x + v2.y*v2.y + v2.z*v2.z + v2.w*v2.w
           + v3.x*v3.x + v3.y*v3.y + v3.z*v3.z + v3.w*v3.w;

#pragma unroll
  for (int off = 32; off > 0; off >>= 1) ss += __shfl_down(ss, off);
  __shared__ float red[4];
  if ((t & 63) == 0) red[t >> 6] = ss;
  __syncthreads();
  float tot = red[0] + red[1] + red[2] + red[3];
  float scale = rsqrtf(tot * (1.0f / HIDDEN) + EPSV);

  ushort4* hr = (ushort4*)(h + (size_t)row * HIDDEN);
  float4 w0 = wr[t], w1 = wr[t + 256], w2 = wr[t + 512];
  ushort4 o;
  o.x = f2bu(v0.x*scale*w0.x); o.y = f2bu(v0.y*scale*w0.y);
  o.z = f2bu(v0.z*scale*w0.z); o.w = f2bu(v0.w*scale*w0.w);
  hr[t] = o;
  o.x = f2bu(v1.x*scale*w1.x); o.y = f2bu(v1.y*scale*w1.y);
  o.z = f2bu(v1.z*scale*w1.z); o.w = f2bu(v1.w*scale*w1.w);
  hr[t + 256] = o;
  o.x = f2bu(v2.x*scale*w2.x); o.y = f2bu(v2.y*scale*w2.y);
  o.z = f2bu(v2.z*scale*w2.z); o.w = f2bu(v2.w*scale*w2.w);
  hr[t + 512] = o;
  if (t < 128) {
    float4 w3 = wr[t + 768];
    o.x = f2bu(v3.x*scale*w3.x); o.y = f2bu(v3.y*scale*w3.y);
    o.z = f2bu(v3.z*scale*w3.z); o.w = f2bu(v3.w*scale*w3.w);
    hr[t + 768] = o;
  }
}

// ---------------- per-token rope table ----------------
__global__ __launch_bounds__(256)
void rope_tab_k(const int* __restrict__ pos, float2* __restrict__ tab) {
  int idx = blockIdx.x * 256 + threadIdx.x;   // NTOK*64
  int t = idx >> 6;
  int i = idx & 63;
  float inv = exp2f(-(float)i * (19.931568569324174f / 64.0f));
  float ang = (float)pos[t] * inv;
  float s, c;
  sincosf(ang, &s, &c);
  tab[idx] = make_float2(c, s);
}

// ---------------- in-place neox rope on q bf16 [NTOK, 28, 128] ----------------
__global__ __launch_bounds__(256)
void rope_apply_k(bf16* __restrict__ q, const float2* __restrict__ tab) {
  const int t = blockIdx.x;
  bf16* qt = q + (size_t)t * NQ;
  const float2* tb = tab + (size_t)t * NPAIR;
  for (int j = threadIdx.x; j < 28 * NPAIR; j += 256) {
    int head = j >> 6;
    int i = j & 63;
    float2 cs = tb[i];
    int base = head * 128 + i;
    float x1 = __bfloat162float(qt[base]);
    float x2 = __bfloat162float(qt[base + 64]);
    qt[base]      = __float2bfloat16(x1 * cs.x - x2 * cs.y);
    qt[base + 64] = __float2bfloat16(x2 * cs.x + x1 * cs.y);
  }
}

// ================= 256x256 8-phase bf16 GEMM (C = A * B^T), m201 port =======
// 8 waves (2M x 4N), BK=64 K-tiles, double-buffered LDS (128 KiB).
// Phase = {ds_read frags | stage 16KB | [lgkm(8)] | BAR | lgkm(0) |
//          setprio+16 MFMA | counted vmcnt | BAR}.
// Swizzle (fix R4): slot' = slot ^ (row & 7) — full 3-bit involution; every
// consecutive-8-lane ds_read_b128 group covers all 8 slots = 32 banks.
// gload_lds dest linear; global source pre-swizzled; ds_read swizzled.
// Stage stagger (tile T_t in buf t&1; B dead after its q0, AH0 after q1,
// AH1 after q3):  ph0:T1.AH1  ph1:T2.Blo ph2:T2.Bhi ph3:T2.AH0 ph4:T2.AH1
//                 ph5:T3.Blo  ph6:T3.Bhi ph7:T3.AH0
// vmcnt ledger (2 instr/stage, verified incl. prologue & endgame):
//   end-ph1: vmcnt(10) -> T0.AH1 landed (staged prev ph4, 5 phases cover)
//   end-ph3: vmcnt(8)  -> T1.B+AH0     (prev ph5-7, 4.5-6.5 phases)
//   end-ph5: vmcnt(10) -> T1.AH1      (ph0, 5 phases)
//   end-ph7: vmcnt(8)  -> T2.B+AH0    (ph1-3, 4-6 phases)
//   last iter: 8 / 2 / 0 / 0.
#define BMT 256
#define BNT 256
#define BKT 64

#define FENCE() asm volatile("" ::: "memory")
#define BAR() do { FENCE(); __builtin_amdgcn_s_barrier(); FENCE(); } while (0)
#define VMW(n) asm volatile("s_waitcnt vmcnt(" #n ")" ::: "memory")

template <int MODE, typename OutT>   // MODE 0: +bias[col] -> OutT; MODE 1: +resid[row,col]
__global__ __launch_bounds__(512, 2)
void gemm256(const bf16* __restrict__ A, const bf16* __restrict__ B,
             const float* __restrict__ aux, OutT* __restrict__ C,
             int M, int N, int K) {
  __shared__ __align__(16) bf16 sA[2][BMT][BKT];   // 64 KiB
  __shared__ __align__(16) bf16 sB[2][BNT][BKT];   // 64 KiB

  const int tid  = threadIdx.x;
  const int wave = tid >> 6;     // 0..7
  const int lane = tid & 63;
  const int wm   = wave >> 2;    // 0..1
  const int wn   = wave & 3;     // 0..3
  const int fr   = lane & 15;
  const int ks   = lane >> 4;
  const int sx   = fr & 7;       // read-side slot XOR = row & 7

  // bijective XCD swizzle, bn-fast within an XCD (A panel hot in XCD L2)
  const int nwg = gridDim.x;           // 448, % 8 == 0
  const int cpx = nwg >> 3;
  const int swz = (blockIdx.x & 7) * cpx + (blockIdx.x >> 3);
  const int gn  = N / BNT;
  const int bm  = (swz / gn) * BMT;
  const int bn  = (swz % gn) * BNT;

  const bf16* Ab = A + (size_t)bm * K;
  const bf16* Bb = B + (size_t)bn * K;

  const int NT = K / BKT;   // 56 (even)

  // one 64-row chunk (8KB): wave w rows [rbase+w*8,+8); lane: row=l>>3, slot=l&7
  const int srw = lane >> 3;    // 0..7  (== row&7 since rbase,wave*8 are x8)
  const int ssl = lane & 7;

  auto stage64 = [&](const bf16* gpanel, int kt, bf16* ldst, int rbase) {
    const int r  = rbase + wave * 8 + srw;            // tile-local row
    const int sg = ssl ^ srw;                         // pre-swizzled source slot
    const bf16* src = gpanel + (size_t)r * K + (size_t)kt * BKT + sg * 8;
    __builtin_amdgcn_global_load_lds(
        (const __attribute__((address_space(1))) void*)src,
        (__attribute__((address_space(3))) void*)(ldst + (size_t)(wave * 8) * BKT),
        16, 0, 0);
  };
  // kinds: 0=A_H0{0,128}, 1=A_H1{64,192}, 2=B_lo{0,64}, 3=B_hi{128,192}
  auto stage16k = [&](int kind, int buf, int kt) {
    if (kt >= NT) return;
    if (kind == 0)      { stage64(Ab, kt, &sA[buf][0][0],   0);   stage64(Ab, kt, &sA[buf][128][0], 128); }
    else if (kind == 1) { stage64(Ab, kt, &sA[buf][64][0],  64);  stage64(Ab, kt, &sA[buf][192][0], 192); }
    else if (kind == 2) { stage64(Bb, kt, &sB[buf][0][0],   0);   stage64(Bb, kt, &sB[buf][64][0],  64); }
    else                { stage64(Bb, kt, &sB[buf][128][0], 128); stage64(Bb, kt, &sB[buf][192][0], 192); }
  };

  f32x4 acc[8][4];
#pragma unroll
  for (int i = 0; i < 8; ++i)
#pragma unroll
    for (int j = 0; j < 4; ++j)
      acc[i][j] = (f32x4){0.f, 0.f, 0.f, 0.f};

  // prologue: tile0 complete (8 loads/wave), tile1 B + A_H0 (6 loads/wave)
  stage16k(2, 0, 0); stage16k(3, 0, 0); stage16k(0, 0, 0); stage16k(1, 0, 0);
  stage16k(2, 1, 1); stage16k(3, 1, 1); stage16k(0, 1, 1);
  VMW(6);   // tile0 fully landed
  BAR();

  bf16x8 bfr[4][2];
  const int nit = NT / 2;   // 28

  for (int it = 0; it < nit; ++it) {
    const bool last = (it == nit - 1);
#pragma unroll
    for (int u = 0; u < 2; ++u) {          // buf/tile half: tile kt = 2*it+u
#pragma unroll
      for (int q = 0; q < 4; ++q) {        // phase within tile
        // ---- ds_read fragments for this phase ----
        bf16x8 afr[2][2];
#pragma unroll
        for (int i = 0; i < 2; ++i)
#pragma unroll
          for (int kk = 0; kk < 2; ++kk) {
            const int R  = wm * 128 + q * 32 + i * 16 + fr;
            const int sp = (kk * 4 + ks) ^ sx;
            afr[i][kk] = *(const bf16x8*)&sA[u][R][sp * 8];
          }
        if (q == 0) {
#pragma unroll
          for (int j = 0; j < 4; ++j)
#pragma unroll
            for (int kk = 0; kk < 2; ++kk) {
              const int R  = wn * 64 + j * 16 + fr;
              const int sp = (kk * 4 + ks) ^ sx;
              bfr[j][kk] = *(const bf16x8*)&sB[u][R][sp * 8];
            }
        }
        // ---- staggered 16KB stage (targets proven-dead regions) ----
        const int ph = u * 4 + q;
        if (ph == 0)      stage16k(1, 1, 2 * it + 1);   // A_H1 of tile 2it+1
        else if (ph == 1) stage16k(2, 0, 2 * it + 2);   // B_lo  tile 2it+2
        else if (ph == 2) stage16k(3, 0, 2 * it + 2);   // B_hi
        else if (ph == 3) stage16k(0, 0, 2 * it + 2);   // A_H0
        else if (ph == 4) stage16k(1, 0, 2 * it + 2);   // A_H1
        else if (ph == 5) stage16k(2, 1, 2 * it + 3);   // B_lo  tile 2it+3
        else if (ph == 6) stage16k(3, 1, 2 * it + 3);   // B_hi
        else              stage16k(0, 1, 2 * it + 3);   // A_H0
        if (q == 0) asm volatile("s_waitcnt lgkmcnt(8)" ::: "memory");  // 12 reads issued
        BAR();
        asm volatile("s_waitcnt lgkmcnt(0)" ::: "memory");
        __builtin_amdgcn_sched_barrier(0);
        __builtin_amdgcn_s_setprio(1);
#pragma unroll
        for (int i = 0; i < 2; ++i)
#pragma unroll
          for (int j = 0; j < 4; ++j)
#pragma unroll
            for (int kk = 0; kk < 2; ++kk)
              acc[q * 2 + i][j] = __builtin_amdgcn_mfma_f32_16x16x32_bf16(
                  afr[i][kk], bfr[j][kk], acc[q * 2 + i][j], 0, 0, 0);
        __builtin_amdgcn_s_setprio(0);
        // ---- counted vmcnt waits (see ledger above) ----
        if (q == 1) {
          if (!last) VMW(10);
          else if (u == 0) VMW(8);
          else VMW(0);
        } else if (q == 3) {
          if (!last) VMW(8);
          else if (u == 0) VMW(2);
          else VMW(0);
        }
        BAR();
      }
    }
  }

  // epilogue: C/D layout col = lane&15, row = 4*(lane>>4) + reg
#pragma unroll
  for (int f = 0; f < 8; ++f) {
    const int rb = bm + wm * 128 + f * 16 + ks * 4;
#pragma unroll
    for (int j = 0; j < 4; ++j) {
      const int col = bn + wn * 64 + j * 16 + fr;
#pragma unroll
      for (int r = 0; r < 4; ++r) {
        const int row = rb + r;
        float v = acc[f][j][r];
        if (MODE == 0) v += aux[col];
        else           v += aux[(size_t)row * N + col];
        stv(&C[(size_t)row * N + col], v);
      }
    }
  }
}

// ---------------- launch ----------------
extern "C" void kernel_launch(void* const* d_in, const int* in_sizes, int n_in,
                              void* d_out, int out_size, void* d_ws, size_t ws_size,
                              hipStream_t stream) {
  (void)in_sizes; (void)n_in; (void)out_size; (void)ws_size;
  const float* x    = (const float*)d_in[0];
  const int*   pos  = (const int*)d_in[1];
  const float* ln_w = (const float*)d_in[2];
  const float* Wq   = (const float*)d_in[3];
  const float* bq   = (const float*)d_in[4];
  const float* Wo   = (const float*)d_in[9];
  float* out = (float*)d_out;

  char* ws = (char*)d_ws;
  size_t off = 0;
  bf16* h    = (bf16*)(ws + off); off += (size_t)NTOK * HIDDEN * sizeof(bf16);
  bf16* q    = (bf16*)(ws + off); off += (size_t)NTOK * NQ * sizeof(bf16);
  bf16* Wqb  = (bf16*)(ws + off); off += (size_t)NQ * HIDDEN * sizeof(bf16);
  bf16* Wob  = (bf16*)(ws + off); off += (size_t)HIDDEN * NQ * sizeof(bf16);
  float2* tab = (float2*)(ws + off); off += (size_t)NTOK * NPAIR * sizeof(float2);

  const int n4 = NQ * HIDDEN / 4;
  cvt_f32_bf16<<<(n4 + 255) / 256, 256, 0, stream>>>(Wq, Wqb, n4);
  cvt_f32_bf16<<<(n4 + 255) / 256, 256, 0, stream>>>(Wo, Wob, n4);
  rmsnorm_k<<<NTOK, 256, 0, stream>>>(x, ln_w, h);
  rope_tab_k<<<(NTOK * NPAIR) / 256, 256, 0, stream>>>(pos, tab);

  const int nblk = (NTOK / BMT) * (NQ / BNT);   // 32 * 14 = 448 (%8 == 0)
  gemm256<0, bf16><<<nblk, 512, 0, stream>>>(h, Wqb, bq, q, NTOK, NQ, HIDDEN);
  rope_apply_k<<<NTOK, 256, 0, stream>>>(q, tab);
  gemm256<1, float><<<nblk, 512, 0, stream>>>(q, Wob, x, out, NTOK, HIDDEN, NQ);
}